// Round 9
// baseline (487.696 us; speedup 1.0000x reference)
//
#include <hip/hip_runtime.h>
#include <math.h>

#define B_  4
#define L_  1024
#define DM  1024
#define DI  1024
#define DS  16
#define DR  64
#define DCV 4
#define NH  4
#define DK  256

#define NCH 32         // scan time-chunks
#define CHL (L_ / NCH) // 32 steps per chunk

typedef __attribute__((ext_vector_type(8))) short short8;
typedef __attribute__((ext_vector_type(4))) float floatx4;

static __device__ __forceinline__ unsigned short f2bf(float f) {
    unsigned int u = __float_as_uint(f);
    u += 0x7fffu + ((u >> 16) & 1u);
    return (unsigned short)(u >> 16);
}
static __device__ __forceinline__ float bf2f(unsigned short s) {
    return __uint_as_float(((unsigned int)s) << 16);
}

// ---------------------------------------------------------------------------
// prep: one dispatch, flat 1D grid (25792 blocks):
//   [0,16384)   conv+silu -> u_bf
//   +4096       cast x -> x_bf
//   +1024       transpose-cast in_proj_w [i][j] -> w_inT [j][i] (bf16)
//   +4288       6 weight cast regions (wq,wk,wv,wo 1024 ea; x_proj 128; dt 64)
// ---------------------------------------------------------------------------
struct PrepArgs {
    const float* xx; const float* cw; const float* cb;
    unsigned short* ub;
    const float* xs; unsigned short* xd;
    const float* ipw; unsigned short* ipt;
    const float* s[6]; unsigned short* d[6];
    int n[6];   // dest elements (mult of 1024)
    int ns[6];  // source elements (<= n, zero-pad past)
};

__global__ __launch_bounds__(256) void prep(PrepArgs pa)
{
    __shared__ float tl[32][33];
    int bid = blockIdx.x, tid = threadIdx.x;
    if (bid < 16384) {
        int idx = bid * 256 + tid;
        int d = idx & (DI - 1);
        int l = (idx >> 10) & (L_ - 1);
        int b = idx >> 20;
        const float* xb = pa.xx + (size_t)b * L_ * DI + d;
        float z = pa.cb[d];
#pragma unroll
        for (int j = 0; j < DCV; j++) {
            int t = l - (DCV - 1) + j;
            if (t >= 0) z += xb[(size_t)t * DI] * pa.cw[d * DCV + j];
        }
        float v = z / (1.0f + __expf(-z));
        pa.ub[idx] = f2bf(v);
        return;
    }
    bid -= 16384;
    if (bid < 4096) {
        int i = (bid * 256 + tid) * 4;
        float4 v = *(const float4*)(pa.xs + i);
        ushort4 o;
        o.x = f2bf(v.x); o.y = f2bf(v.y); o.z = f2bf(v.z); o.w = f2bf(v.w);
        *(ushort4*)(pa.xd + i) = o;
        return;
    }
    bid -= 4096;
    if (bid < 1024) {
        // transpose-cast in_proj: 32x32 tile
        int ti = bid >> 5, tj = bid & 31;
        int i0 = ti * 32, j0 = tj * 32;
        int r = tid >> 3, c4 = (tid & 7) * 4;
        const float* src = pa.ipw + (size_t)(i0 + r) * 1024 + j0 + c4;
        float4 v = *(const float4*)src;
        tl[r][c4 + 0] = v.x; tl[r][c4 + 1] = v.y;
        tl[r][c4 + 2] = v.z; tl[r][c4 + 3] = v.w;
        __syncthreads();
        unsigned short* dst = pa.ipt + (size_t)(j0 + r) * 1024 + i0 + c4;
        ushort4 o;
        o.x = f2bf(tl[c4 + 0][r]); o.y = f2bf(tl[c4 + 1][r]);
        o.z = f2bf(tl[c4 + 2][r]); o.w = f2bf(tl[c4 + 3][r]);
        *(ushort4*)dst = o;
        return;
    }
    bid -= 1024;
#pragma unroll
    for (int r = 0; r < 6; r++) {
        int nb = pa.n[r] >> 10;
        if (bid < nb) {
            int i = (bid * 256 + tid) * 4;
            int ns = pa.ns[r];
            const float* s = pa.s[r];
            ushort4 o;
            if (i + 4 <= ns) {
                float4 v = *(const float4*)(s + i);
                o.x = f2bf(v.x); o.y = f2bf(v.y); o.z = f2bf(v.z); o.w = f2bf(v.w);
            } else {
                float v[4];
#pragma unroll
                for (int j = 0; j < 4; j++) v[j] = (i + j < ns) ? s[i + j] : 0.f;
                o.x = f2bf(v[0]); o.y = f2bf(v[1]); o.z = f2bf(v[2]); o.w = f2bf(v[3]);
            }
            *(ushort4*)(pa.d[r] + i) = o;
            return;
        }
        bid -= nb;
    }
}

// ---------------------------------------------------------------------------
// Multi-descriptor bf16 MFMA GEMM: per z, C = act(A @ W^T * scale + bias)
// mode & 3: 0 = fp32 out, 1 = bf16 out. mode & 4: softplus.
// ---------------------------------------------------------------------------
struct GDesc {
    const unsigned short* A;
    const unsigned short* W;
    const float* bias;
    float* Cf;
    unsigned short* Cb;
    int K, lda, ldw, ldc, ldc2;
    int mode;
    float scale;
    int gx, gy;
};
struct GArgs { GDesc g[3]; };

__global__ __launch_bounds__(256) void gemm_multi(GArgs ga)
{
    GDesc g = ga.g[blockIdx.z];
    if ((int)blockIdx.x >= g.gx || (int)blockIdx.y >= g.gy) return;

    __shared__ __align__(16) unsigned short Asm[128 * 32];
    __shared__ __align__(16) unsigned short Bsm[128 * 32];

    int tid = threadIdx.x;
    int wid = tid >> 6;
    int lane = tid & 63;
    int wm = wid & 1, wn = wid >> 1;
    int lr = lane & 15, quad = lane >> 4;

    const unsigned short* Ab = g.A + (size_t)blockIdx.y * 128 * g.lda;
    const unsigned short* Wb = g.W + (size_t)blockIdx.x * 128 * g.ldw;

    int srow = tid >> 2;
    int scol = (tid & 3) * 8;
    const unsigned short* Ap = Ab + (size_t)srow * g.lda + scol;
    const unsigned short* Wp = Wb + (size_t)srow * g.ldw + scol;

    unsigned short* lA0 = &Asm[(wid * 16) * 32];
    unsigned short* lA1 = &Asm[(64 + wid * 16) * 32];
    unsigned short* lB0 = &Bsm[(wid * 16) * 32];
    unsigned short* lB1 = &Bsm[(64 + wid * 16) * 32];

    floatx4 acc[4][4];
#pragma unroll
    for (int i = 0; i < 4; i++)
#pragma unroll
        for (int j = 0; j < 4; j++) acc[i][j] = (floatx4){0.f, 0.f, 0.f, 0.f};

#define GLL(gp, lp) __builtin_amdgcn_global_load_lds( \
        (const __attribute__((address_space(1))) void*)(gp), \
        (__attribute__((address_space(3))) void*)(lp), 16, 0, 0)

    for (int k0 = 0; k0 < g.K; k0 += 32) {
        GLL(Ap, lA0);
        GLL(Ap + (size_t)64 * g.lda, lA1);
        GLL(Wp, lB0);
        GLL(Wp + (size_t)64 * g.ldw, lB1);
        Ap += 32; Wp += 32;
        __syncthreads();

        short8 af[4], bf[4];
#pragma unroll
        for (int mt = 0; mt < 4; mt++)
            af[mt] = *(const short8*)&Asm[(wm * 64 + mt * 16 + lr) * 32 + quad * 8];
#pragma unroll
        for (int nt = 0; nt < 4; nt++)
            bf[nt] = *(const short8*)&Bsm[(wn * 64 + nt * 16 + lr) * 32 + quad * 8];
#pragma unroll
        for (int mt = 0; mt < 4; mt++)
#pragma unroll
            for (int nt = 0; nt < 4; nt++)
                acc[mt][nt] = __builtin_amdgcn_mfma_f32_16x16x32_bf16(
                    af[mt], bf[nt], acc[mt][nt], 0, 0, 0);
        __syncthreads();
    }
#undef GLL

    int bm = blockIdx.y * 128, bn = blockIdx.x * 128;
    int m = g.mode & 3;
#pragma unroll
    for (int mt = 0; mt < 4; mt++) {
#pragma unroll
        for (int nt = 0; nt < 4; nt++) {
            int row0 = bm + wm * 64 + mt * 16 + quad * 4;
            int col = bn + wn * 64 + nt * 16 + lr;
            float bv = g.bias ? g.bias[col] : 0.f;
#pragma unroll
            for (int i = 0; i < 4; i++) {
                float v = acc[mt][nt][i] * g.scale + bv;
                if (g.mode & 4) v = (v > 15.f) ? v : log1pf(__expf(v));
                if (m == 0) g.Cf[(size_t)(row0 + i) * g.ldc + col] = v;
                else        g.Cb[(size_t)(row0 + i) * g.ldc + col] = f2bf(v);
            }
        }
    }
}

// ---------------------------------------------------------------------------
// Batched-strided bf16 MFMA GEMM (attention): z -> b=z>>2, h=z&3
// ---------------------------------------------------------------------------
__global__ __launch_bounds__(256) void gemm_batched(
    const unsigned short* __restrict__ A, const unsigned short* __restrict__ W,
    unsigned short* __restrict__ C,
    int K, int lda, int ldw, int ldc,
    long long sA1, long long sA2, long long sW1, long long sW2,
    long long sC1, long long sC2, float scale)
{
    __shared__ __align__(16) unsigned short Asm[128 * 32];
    __shared__ __align__(16) unsigned short Bsm[128 * 32];

    int z = blockIdx.z;
    long long bq = z >> 2, hq = z & 3;
    int tid = threadIdx.x;
    int wid = tid >> 6;
    int lane = tid & 63;
    int wm = wid & 1, wn = wid >> 1;
    int lr = lane & 15, quad = lane >> 4;

    const unsigned short* Ab = A + bq * sA1 + hq * sA2 + (size_t)blockIdx.y * 128 * lda;
    const unsigned short* Wb = W + bq * sW1 + hq * sW2 + (size_t)blockIdx.x * 128 * ldw;

    int srow = tid >> 2;
    int scol = (tid & 3) * 8;
    const unsigned short* Ap = Ab + (size_t)srow * lda + scol;
    const unsigned short* Wp = Wb + (size_t)srow * ldw + scol;

    unsigned short* lA0 = &Asm[(wid * 16) * 32];
    unsigned short* lA1 = &Asm[(64 + wid * 16) * 32];
    unsigned short* lB0 = &Bsm[(wid * 16) * 32];
    unsigned short* lB1 = &Bsm[(64 + wid * 16) * 32];

    floatx4 acc[4][4];
#pragma unroll
    for (int i = 0; i < 4; i++)
#pragma unroll
        for (int j = 0; j < 4; j++) acc[i][j] = (floatx4){0.f, 0.f, 0.f, 0.f};

#define GLL(gp, lp) __builtin_amdgcn_global_load_lds( \
        (const __attribute__((address_space(1))) void*)(gp), \
        (__attribute__((address_space(3))) void*)(lp), 16, 0, 0)

    for (int k0 = 0; k0 < K; k0 += 32) {
        GLL(Ap, lA0);
        GLL(Ap + (size_t)64 * lda, lA1);
        GLL(Wp, lB0);
        GLL(Wp + (size_t)64 * ldw, lB1);
        Ap += 32; Wp += 32;
        __syncthreads();

        short8 af[4], bf[4];
#pragma unroll
        for (int mt = 0; mt < 4; mt++)
            af[mt] = *(const short8*)&Asm[(wm * 64 + mt * 16 + lr) * 32 + quad * 8];
#pragma unroll
        for (int nt = 0; nt < 4; nt++)
            bf[nt] = *(const short8*)&Bsm[(wn * 64 + nt * 16 + lr) * 32 + quad * 8];
#pragma unroll
        for (int mt = 0; mt < 4; mt++)
#pragma unroll
            for (int nt = 0; nt < 4; nt++)
                acc[mt][nt] = __builtin_amdgcn_mfma_f32_16x16x32_bf16(
                    af[mt], bf[nt], acc[mt][nt], 0, 0, 0);
        __syncthreads();
    }
#undef GLL

    long long coff = bq * sC1 + hq * sC2;
    int bm = blockIdx.y * 128, bn = blockIdx.x * 128;
    unsigned short* Cb = C + coff;

#pragma unroll
    for (int mt = 0; mt < 4; mt++) {
#pragma unroll
        for (int nt = 0; nt < 4; nt++) {
            int row0 = bm + wm * 64 + mt * 16 + quad * 4;
            int col = bn + wn * 64 + nt * 16 + lr;
#pragma unroll
            for (int i = 0; i < 4; i++)
                Cb[(size_t)(row0 + i) * ldc + col] = f2bf(acc[mt][nt][i] * scale);
        }
    }
}

// ---------------------------------------------------------------------------
// Scan phase A: one thread = (b,d,chunk). u and xdbl are bf16.
// ---------------------------------------------------------------------------
__global__ __launch_bounds__(256) void scan_a(
    const float* __restrict__ delta, const unsigned short* __restrict__ u,
    const unsigned short* __restrict__ xdbl, const float* __restrict__ A_log,
    float* __restrict__ Hc, float* __restrict__ sumdv)
{
    int gid = blockIdx.x * 256 + threadIdx.x;
    int c = gid >> 12;
    int bd = gid & 4095;
    int b = bd >> 10, d = bd & 1023;

    float a[16];
#pragma unroll
    for (int j = 0; j < 4; j++) {
        float4 al = *(const float4*)(A_log + d * 16 + j * 4);
        a[j * 4 + 0] = -__expf(al.x); a[j * 4 + 1] = -__expf(al.y);
        a[j * 4 + 2] = -__expf(al.z); a[j * 4 + 3] = -__expf(al.w);
    }
    float h[16];
#pragma unroll
    for (int n = 0; n < 16; n++) h[n] = 0.f;
    float sd = 0.f;

    int t0 = c * CHL;
    const float* dp = delta + ((size_t)(b * L_) + t0) * DI + d;
    const unsigned short* up = u + ((size_t)(b * L_) + t0) * DI + d;
    const unsigned short* xp = xdbl + ((size_t)(b * L_) + t0) * 128;

#pragma unroll 4
    for (int t = 0; t < CHL; t++) {
        float dv = dp[t * DI];
        float uv = bf2f(up[t * DI]);
        float duv = dv * uv;
        sd += dv;
        short8 b0 = *(const short8*)(xp + t * 128 + 64);
        short8 b1 = *(const short8*)(xp + t * 128 + 72);
        float Bv[16];
#pragma unroll
        for (int j = 0; j < 8; j++) {
            Bv[j] = bf2f((unsigned short)b0[j]);
            Bv[8 + j] = bf2f((unsigned short)b1[j]);
        }
#pragma unroll
        for (int n = 0; n < 16; n++)
            h[n] = __expf(dv * a[n]) * h[n] + duv * Bv[n];
    }

    float* hp = Hc + ((size_t)c * 4096 + bd) * 16;
#pragma unroll
    for (int j = 0; j < 4; j++)
        *(float4*)(hp + j * 4) = make_float4(h[j * 4], h[j * 4 + 1], h[j * 4 + 2], h[j * 4 + 3]);
    sumdv[c * 4096 + bd] = sd;
}

// ---------------------------------------------------------------------------
// Scan phase B: in-place combine — Hc[c][bd][*] becomes chunk START state
// ---------------------------------------------------------------------------
__global__ __launch_bounds__(256) void scan_b(
    float* __restrict__ Hc, const float* __restrict__ sumdv,
    const float* __restrict__ A_log)
{
    int bd = blockIdx.x * 256 + threadIdx.x;
    int d = bd & 1023;

    float a[16];
#pragma unroll
    for (int j = 0; j < 4; j++) {
        float4 al = *(const float4*)(A_log + d * 16 + j * 4);
        a[j * 4 + 0] = -__expf(al.x); a[j * 4 + 1] = -__expf(al.y);
        a[j * 4 + 2] = -__expf(al.z); a[j * 4 + 3] = -__expf(al.w);
    }
    float H[16];
#pragma unroll
    for (int n = 0; n < 16; n++) H[n] = 0.f;

    for (int c = 0; c < NCH; c++) {
        float* hp = Hc + ((size_t)c * 4096 + bd) * 16;
        float sdv = sumdv[c * 4096 + bd];
        float hc[16];
#pragma unroll
        for (int j = 0; j < 4; j++) {
            float4 q = *(const float4*)(hp + j * 4);
            hc[j * 4 + 0] = q.x; hc[j * 4 + 1] = q.y; hc[j * 4 + 2] = q.z; hc[j * 4 + 3] = q.w;
        }
#pragma unroll
        for (int j = 0; j < 4; j++)
            *(float4*)(hp + j * 4) = make_float4(H[j * 4], H[j * 4 + 1], H[j * 4 + 2], H[j * 4 + 3]);
#pragma unroll
        for (int n = 0; n < 16; n++)
            H[n] = __expf(a[n] * sdv) * H[n] + hc[n];
    }
}

// ---------------------------------------------------------------------------
// Scan phase C: re-run chunk from start state, emit y (bf16)
// ---------------------------------------------------------------------------
__global__ __launch_bounds__(256) void scan_c(
    const float* __restrict__ delta, const unsigned short* __restrict__ u,
    const unsigned short* __restrict__ xdbl, const float* __restrict__ A_log,
    const float* __restrict__ Dv, const float* __restrict__ Hstart,
    unsigned short* __restrict__ y)
{
    int gid = blockIdx.x * 256 + threadIdx.x;
    int c = gid >> 12;
    int bd = gid & 4095;
    int b = bd >> 10, d = bd & 1023;

    float a[16];
#pragma unroll
    for (int j = 0; j < 4; j++) {
        float4 al = *(const float4*)(A_log + d * 16 + j * 4);
        a[j * 4 + 0] = -__expf(al.x); a[j * 4 + 1] = -__expf(al.y);
        a[j * 4 + 2] = -__expf(al.z); a[j * 4 + 3] = -__expf(al.w);
    }
    float h[16];
    const float* hp = Hstart + ((size_t)c * 4096 + bd) * 16;
#pragma unroll
    for (int j = 0; j < 4; j++) {
        float4 q = *(const float4*)(hp + j * 4);
        h[j * 4 + 0] = q.x; h[j * 4 + 1] = q.y; h[j * 4 + 2] = q.z; h[j * 4 + 3] = q.w;
    }
    float Dd = Dv[d];

    int t0 = c * CHL;
    const float* dp = delta + ((size_t)(b * L_) + t0) * DI + d;
    const unsigned short* up = u + ((size_t)(b * L_) + t0) * DI + d;
    const unsigned short* xp = xdbl + ((size_t)(b * L_) + t0) * 128;
    unsigned short* yp = y + ((size_t)(b * L_) + t0) * DI + d;

#pragma unroll 4
    for (int t = 0; t < CHL; t++) {
        float dv = dp[t * DI];
        float uv = bf2f(up[t * DI]);
        float duv = dv * uv;
        short8 b0 = *(const short8*)(xp + t * 128 + 64);
        short8 b1 = *(const short8*)(xp + t * 128 + 72);
        short8 c0 = *(const short8*)(xp + t * 128 + 80);
        short8 c1 = *(const short8*)(xp + t * 128 + 88);
        float Bv[16], Cv[16];
#pragma unroll
        for (int j = 0; j < 8; j++) {
            Bv[j] = bf2f((unsigned short)b0[j]);
            Bv[8 + j] = bf2f((unsigned short)b1[j]);
            Cv[j] = bf2f((unsigned short)c0[j]);
            Cv[8 + j] = bf2f((unsigned short)c1[j]);
        }
        float ys = 0.f;
#pragma unroll
        for (int n = 0; n < 16; n++) {
            h[n] = __expf(dv * a[n]) * h[n] + duv * Bv[n];
            ys += h[n] * Cv[n];
        }
        yp[t * DI] = f2bf(ys + uv * Dd);
    }
}

// ---------------------------------------------------------------------------
// post_s: fused row-softmax of S (blocks [0,4096)) and V->VT transpose
// (blocks [4096,8192)), one dispatch.
// ---------------------------------------------------------------------------
__global__ __launch_bounds__(256) void post_s(
    unsigned short* __restrict__ S, const unsigned short* __restrict__ V,
    unsigned short* __restrict__ VT)
{
    __shared__ unsigned short tl[32][36];
    int bid = blockIdx.x, tid = threadIdx.x;
    if (bid < 4096) {
        int row = bid * 4 + (tid >> 6);
        int lane = tid & 63;
        unsigned short* p = S + (size_t)row * 1024;
        float v[16];
#pragma unroll
        for (int ch = 0; ch < 4; ch++) {
            ushort4 u4 = *(const ushort4*)(p + ch * 256 + lane * 4);
            v[ch * 4 + 0] = bf2f(u4.x); v[ch * 4 + 1] = bf2f(u4.y);
            v[ch * 4 + 2] = bf2f(u4.z); v[ch * 4 + 3] = bf2f(u4.w);
        }
        float m = -1e30f;
#pragma unroll
        for (int i = 0; i < 16; i++) m = fmaxf(m, v[i]);
#pragma unroll
        for (int off = 32; off >= 1; off >>= 1) m = fmaxf(m, __shfl_xor(m, off));
        float s = 0.f;
#pragma unroll
        for (int i = 0; i < 16; i++) { v[i] = __expf(v[i] - m); s += v[i]; }
#pragma unroll
        for (int off = 32; off >= 1; off >>= 1) s += __shfl_xor(s, off);
        float inv = 1.0f / s;
#pragma unroll
        for (int ch = 0; ch < 4; ch++) {
            ushort4 o;
            o.x = f2bf(v[ch * 4 + 0] * inv); o.y = f2bf(v[ch * 4 + 1] * inv);
            o.z = f2bf(v[ch * 4 + 2] * inv); o.w = f2bf(v[ch * 4 + 3] * inv);
            *(ushort4*)(p + ch * 256 + lane * 4) = o;
        }
        return;
    }
    bid -= 4096;
    // V transpose: bid -> (l-tile 32, d-tile 8, bh 16)
    int lx = bid & 31, dy = (bid >> 5) & 7, bh = bid >> 8;
    int b = bh >> 2, h = bh & 3;
    int l0 = lx * 32, d0 = dy * 32;
    int r = tid >> 3, c4 = (tid & 7) * 4;

    const unsigned short* src = V + ((size_t)(b * L_ + l0 + r)) * 1024 + h * DK + d0 + c4;
    ushort4 v = *(const ushort4*)src;
    tl[r][c4 + 0] = v.x; tl[r][c4 + 1] = v.y; tl[r][c4 + 2] = v.z; tl[r][c4 + 3] = v.w;
    __syncthreads();

    unsigned short* dst = VT + ((size_t)bh * DK + d0 + r) * L_ + l0 + c4;
    ushort4 o;
    o.x = tl[c4 + 0][r]; o.y = tl[c4 + 1][r]; o.z = tl[c4 + 2][r]; o.w = tl[c4 + 3][r];
    *(ushort4*)dst = o;
}

// ---------------------------------------------------------------------------
extern "C" void kernel_launch(void* const* d_in, const int* in_sizes, int n_in,
                              void* d_out, int out_size, void* d_ws, size_t ws_size,
                              hipStream_t stream)
{
    const float* x         = (const float*)d_in[0];
    const float* xx        = (const float*)d_in[1];
    const float* in_proj_w = (const float*)d_in[2];
    const float* conv_w    = (const float*)d_in[3];
    const float* conv_b    = (const float*)d_in[4];
    const float* x_proj_w  = (const float*)d_in[5];
    const float* dt_proj_w = (const float*)d_in[6];
    const float* dt_proj_b = (const float*)d_in[7];
    const float* A_log     = (const float*)d_in[8];
    const float* Dvec      = (const float*)d_in[9];
    const float* wq        = (const float*)d_in[10];
    const float* bq        = (const float*)d_in[11];
    const float* wk        = (const float*)d_in[12];
    const float* bk        = (const float*)d_in[13];
    const float* wv        = (const float*)d_in[14];
    const float* bv        = (const float*)d_in[15];
    const float* wo        = (const float*)d_in[16];
    const float* bo        = (const float*)d_in[17];
    float* out = (float*)d_out;

    char* w = (char*)d_ws;
    const size_t MB = 1024 * 1024, KB = 1024;
    float*          Hc     = (float*)(w + 0);                // 8 MB (scan)
    float*          delta  = (float*)(w + 16 * MB);          // 16 MB fp32
    unsigned short* Sbuf   = (unsigned short*)(w + 0);       // 32 MB (after scan)
    unsigned short* x_bf   = (unsigned short*)(w + 32 * MB); // 8 MB
    unsigned short* Q_bf   = (unsigned short*)(w + 40 * MB); // 8 MB
    unsigned short* y_bf   = (unsigned short*)(w + 48 * MB); // 8 MB -> AO
    unsigned short* AO     = y_bf;
    unsigned short* K_bf   = (unsigned short*)(w + 56 * MB); // 8 MB
    unsigned short* V_bf   = (unsigned short*)(w + 64 * MB); // 8 MB
    unsigned short* u_bf   = (unsigned short*)(w + 72 * MB); // 8 MB -> VT
    unsigned short* VT     = u_bf;
    unsigned short* w_qc   = (unsigned short*)(w + 80 * MB); // 2 MB combined wq@in_proj
    unsigned short* xdblb  = (unsigned short*)(w + 82 * MB); // 1 MB
    unsigned short* w_inT  = (unsigned short*)(w + 83 * MB); // 2 MB in_proj^T
    unsigned short* w_q    = (unsigned short*)(w + 85 * MB); // 2 MB
    unsigned short* w_k    = (unsigned short*)(w + 87 * MB); // 2 MB
    unsigned short* w_v    = (unsigned short*)(w + 89 * MB); // 2 MB
    unsigned short* w_o    = (unsigned short*)(w + 91 * MB); // 2 MB
    unsigned short* w_xp   = (unsigned short*)(w + 93 * MB);            // 256 KB
    unsigned short* w_dt   = (unsigned short*)(w + 93 * MB + 256 * KB); // 128 KB
    float*          sumdv  = (float*)(w + 93 * MB + 384 * KB);          // 512 KB

    dim3 blk(256);
    const long long LL = L_;

    // 1. prep: conv+silu, casts, in_proj transpose-cast
    PrepArgs pa;
    pa.xx = xx; pa.cw = conv_w; pa.cb = conv_b; pa.ub = u_bf;
    pa.xs = x; pa.xd = x_bf;
    pa.ipw = in_proj_w; pa.ipt = w_inT;
    pa.s[0] = wq;        pa.d[0] = w_q;  pa.n[0] = 1048576; pa.ns[0] = 1048576;
    pa.s[1] = wk;        pa.d[1] = w_k;  pa.n[1] = 1048576; pa.ns[1] = 1048576;
    pa.s[2] = wv;        pa.d[2] = w_v;  pa.n[2] = 1048576; pa.ns[2] = 1048576;
    pa.s[3] = wo;        pa.d[3] = w_o;  pa.n[3] = 1048576; pa.ns[3] = 1048576;
    pa.s[4] = x_proj_w;  pa.d[4] = w_xp; pa.n[4] = 131072;  pa.ns[4] = 98304;
    pa.s[5] = dt_proj_w; pa.d[5] = w_dt; pa.n[5] = 65536;   pa.ns[5] = 65536;
    prep<<<dim3(25792), blk, 0, stream>>>(pa);

    // 2. x_dbl = u @ x_proj^T (bf16) || Wc = wq @ in_proj (combined Q weight)
    {
        GArgs ga = {};
        ga.g[0] = (GDesc){u_bf, w_xp, nullptr, nullptr, xdblb,
                          1024, 1024, 1024, 128, 0, 1, 1.0f, 1, 32};
        ga.g[1] = (GDesc){w_q, w_inT, nullptr, nullptr, w_qc,
                          1024, 1024, 1024, 1024, 0, 1, 1.0f, 8, 8};
        gemm_multi<<<dim3(8, 32, 2), blk, 0, stream>>>(ga);
    }
    // 3. dt_proj (softplus) -> delta fp32
    {
        GArgs ga = {};
        ga.g[0] = (GDesc){xdblb, w_dt, dt_proj_b, delta, nullptr,
                          64, 128, 64, 1024, 0, 0 | 4, 1.0f, 8, 32};
        gemm_multi<<<dim3(8, 32, 1), blk, 0, stream>>>(ga);
    }
    // 4-6. chunked scan (bf16 u / B / C)
    scan_a<<<dim3(512), blk, 0, stream>>>(delta, u_bf, xdblb, A_log, Hc, sumdv);
    scan_b<<<dim3(16), blk, 0, stream>>>(Hc, sumdv, A_log);
    scan_c<<<dim3(512), blk, 0, stream>>>(delta, u_bf, xdblb, A_log, Dvec, Hc, y_bf);

    // 7. Q = x @ Wc^T + bq || K || V
    {
        GArgs ga = {};
        ga.g[0] = (GDesc){x_bf, w_qc, bq, nullptr, Q_bf, 1024, 1024, 1024, 1024, 0, 1, 1.0f, 8, 32};
        ga.g[1] = (GDesc){y_bf, w_k, bk, nullptr, K_bf, 1024, 1024, 1024, 1024, 0, 1, 1.0f, 8, 32};
        ga.g[2] = (GDesc){y_bf, w_v, bv, nullptr, V_bf, 1024, 1024, 1024, 1024, 0, 1, 1.0f, 8, 32};
        gemm_multi<<<dim3(8, 32, 3), blk, 0, stream>>>(ga);
    }
    // 8. S = Q @ K^T * scale (Sbuf aliases dead Hc/delta)
    gemm_batched<<<dim3(8, 8, 16), blk, 0, stream>>>(Q_bf, K_bf, Sbuf,
        DK, 1024, 1024, 1024,
        LL * 1024, 256, LL * 1024, 256,
        4 * LL * 1024, LL * 1024, 0.0625f);
    // 9. softmax(S) + V->VT (VT aliases dead u_bf)
    post_s<<<dim3(8192), blk, 0, stream>>>(Sbuf, V_bf, VT);
    // 10. AO = P @ V
    gemm_batched<<<dim3(2, 8, 16), blk, 0, stream>>>(Sbuf, VT, AO,
        1024, 1024, 1024, 1024,
        4 * LL * 1024, LL * 1024,
        4 * (long long)DK * 1024, (long long)DK * 1024,
        LL * 1024, 256, 1.0f);
    // 11. out = AO @ wo^T + bo (fp32)
    {
        GArgs ga = {};
        ga.g[0] = (GDesc){AO, w_o, bo, out, nullptr, 1024, 1024, 1024, 1024, 0, 0, 1.0f, 8, 32};
        gemm_multi<<<dim3(8, 32, 1), blk, 0, stream>>>(ga);
    }
}